// Round 6
// baseline (136.870 us; speedup 1.0000x reference)
//
#include <hip/hip_runtime.h>
#include <hip/hip_bf16.h>

// MHA forward: B=4, S=1024, D=1024, H=16, DK=64.
// v6: bf16 weight pre-convert + global_load_lds (swizzled-source) B-staging;
// gemm_out fully glds-staged; attn v5 swapped-QK^T flash (unchanged).

typedef __bf16 bf16x8 __attribute__((ext_vector_type(8)));
typedef float f32x4 __attribute__((ext_vector_type(4)));
typedef unsigned short us8 __attribute__((ext_vector_type(8)));
typedef unsigned short us4 __attribute__((ext_vector_type(4)));

#define MFMA(a, b, c) __builtin_amdgcn_mfma_f32_16x16x32_bf16(a, b, c, 0, 0, 0)
#define EXP2(x) __builtin_amdgcn_exp2f(x)

__device__ __forceinline__ unsigned short f2b(float f) {
  return __builtin_bit_cast(unsigned short, __float2bfloat16(f));
}
__device__ __forceinline__ float b2f(unsigned short u) {
  return __builtin_bit_cast(float, (unsigned)u << 16);
}
__device__ __forceinline__ bf16x8 ldbf8(const unsigned short* p) {
  return __builtin_bit_cast(bf16x8, *reinterpret_cast<const us8*>(p));
}
__device__ __forceinline__ us8 cvt8(float4 a, float4 b) {
  us8 o;
  o[0] = f2b(a.x); o[1] = f2b(a.y); o[2] = f2b(a.z); o[3] = f2b(a.w);
  o[4] = f2b(b.x); o[5] = f2b(b.y); o[6] = f2b(b.z); o[7] = f2b(b.w);
  return o;
}
__device__ __forceinline__ void glds16(const void* g, void* l) {
  __builtin_amdgcn_global_load_lds(
      (const __attribute__((address_space(1))) unsigned int*)g,
      (__attribute__((address_space(3))) unsigned int*)l, 16, 0, 0);
}

// prep: [0,4096) blocks convert mask -> Mf (swapped QK^T C-frag order, *(-1e9*log2e));
//       [4096,5632) convert wq/wk/wv f32 -> bf16 into Wb (3 x 1M elements).
__global__ __launch_bounds__(256)
void prep(const int* __restrict__ mask, const float* __restrict__ wq,
          const float* __restrict__ wk, const float* __restrict__ wv,
          unsigned short* __restrict__ Mf, unsigned short* __restrict__ Wb) {
  const int bid = blockIdx.x, tid = threadIdx.x;
  if (bid < 4096) {
    const int idx = bid * 256 + tid;
    const int wl = idx & 63, tile = idx >> 6;
    const int kt = tile & 63, qt = (tile >> 6) & 63, b = tile >> 12;
    const int lr = wl & 15, lg = wl >> 4;
    const int4 mv = *reinterpret_cast<const int4*>(
        mask + (size_t)(b * 1024 + qt * 16 + lr) * 1024 + kt * 16 + lg * 4);
    us4 o;
    o[0] = mv.x ? 0xCEACu : 0u;
    o[1] = mv.y ? 0xCEACu : 0u;
    o[2] = mv.z ? 0xCEACu : 0u;
    o[3] = mv.w ? 0xCEACu : 0u;
    *reinterpret_cast<us4*>(Mf + (size_t)idx * 4) = o;
  } else {
    const int b2 = bid - 4096;
    const int widx = b2 >> 9;
    const float* src = (widx == 0) ? wq : (widx == 1) ? wk : wv;
    const size_t off = (size_t)(b2 & 511) * 2048 + tid * 8;
    const float4* p = reinterpret_cast<const float4*>(src + off);
    *reinterpret_cast<us8*>(Wb + (size_t)widx * 1048576 + off) = cvt8(p[0], p[1]);
  }
}

// single f32->bf16 1Mx convert (for wo, after attn frees Vf space)
__global__ __launch_bounds__(256)
void cvt_w(const float* __restrict__ src, unsigned short* __restrict__ dst) {
  const size_t off = (size_t)blockIdx.x * 2048 + threadIdx.x * 8;
  const float4* p = reinterpret_cast<const float4*>(src + off);
  *reinterpret_cast<us8*>(dst + off) = cvt8(p[0], p[1]);
}

// ---- shared compute macro: As [128][64] / Bs [64][64] bf16, XOR-swizzled rows,
// 4 waves 2x2 (wave tile 64x32). Reads apply byte^((row&7)<<4).
#define GEMM_COMPUTE_HALF(buf, h2)                                             \
  {                                                                            \
    bf16x8 af[4], bfr[2];                                                      \
    _Pragma("unroll") for (int m = 0; m < 4; ++m) {                            \
      const int row = wr * 64 + m * 16 + lr;                                   \
      af[m] = ldbf8((const unsigned short*)((char*)&As[buf][0] + row * 128 +   \
                                            (((h2) * 64 + lg * 16) ^ swzc)));  \
    }                                                                          \
    _Pragma("unroll") for (int n = 0; n < 2; ++n) {                            \
      const int row = wc * 32 + n * 16 + lr;                                   \
      bfr[n] = ldbf8((const unsigned short*)((char*)&Bs[buf][0] + row * 128 +  \
                                             (((h2) * 64 + lg * 16) ^ swzc))); \
    }                                                                          \
    _Pragma("unroll") for (int m = 0; m < 4; ++m)                              \
        _Pragma("unroll") for (int n = 0; n < 2; ++n)                          \
        acc[m][n] = MFMA(af[m], bfr[n], acc[m][n]);                            \
  }

#define STA(buf, it, v)                                                        \
  *reinterpret_cast<us8*>((char*)&As[buf][0] + (srow + (it) * 32) * 128 +      \
                          (scolb ^ (((srow + (it) * 32) & 7) << 4))) = (v)

// Fused QKV projection. A: f32 (reg-staged, T14 split); B: bf16 weights via
// swizzled-source global_load_lds. z selects {query->Qb, key->Kf, value->Vf}.
__global__ __launch_bounds__(256)
void gemm_qkv(const float* __restrict__ Aq, const float* __restrict__ Akk,
              const float* __restrict__ Av, const unsigned short* __restrict__ Wb,
              const float* __restrict__ bq, const float* __restrict__ bk,
              const float* __restrict__ bv, unsigned short* __restrict__ Qb,
              unsigned short* __restrict__ Kf, unsigned short* __restrict__ Vf,
              float qscale) {
  constexpr int K = 1024, N = 1024;
  __shared__ __align__(16) unsigned short As[2][128 * 64];
  __shared__ __align__(16) unsigned short Bs[2][64 * 64];
  const int z = blockIdx.z;
  const float* A = (z == 0) ? Aq : (z == 1) ? Akk : Av;
  const unsigned short* Bw = Wb + (size_t)z * 1048576;
  const float* bias = (z == 0) ? bq : (z == 1) ? bk : bv;
  const int bm = blockIdx.x * 128, bn = blockIdx.y * 64;
  const int t = threadIdx.x;
  const int w = t >> 6, lane = t & 63, lr = lane & 15, lg = lane >> 4;
  const int wr = w >> 1, wc = w & 1;
  const int srow = t >> 3, scolb = (t & 7) * 16, scole = (t & 7) * 8;
  const int swzc = (lr & 7) << 4;

  f32x4 acc[4][2];
#pragma unroll
  for (int m = 0; m < 4; ++m)
#pragma unroll
    for (int n = 0; n < 2; ++n) acc[m][n] = f32x4{0.f, 0.f, 0.f, 0.f};

  // B staging: pre-swizzled global source + linear glds dest (rule #21)
  auto stageB = [&](int k0, int buf) {
#pragma unroll
    for (int it = 0; it < 2; ++it) {
      const int s = it * 256 + t, row = s >> 3, cb = (s & 7) * 16;
      const char* g = (const char*)Bw + ((size_t)(bn + row) * 1024 + k0) * 2 +
                      (cb ^ ((row & 7) << 4));
      char* l = (char*)&Bs[buf][0] + (it * 256 + w * 64) * 16;
      glds16(g, l);
    }
  };

  // prologue
  {
#pragma unroll
    for (int it = 0; it < 4; ++it) {
      const float4* p =
          reinterpret_cast<const float4*>(A + (size_t)(bm + srow + it * 32) * K + scole);
      STA(0, it, cvt8(p[0], p[1]));
    }
    stageB(0, 0);
  }
  __syncthreads();

  for (int c = 0; c < 16; ++c) {
    const int buf = c & 1;
    float4 fa[8];
    if (c < 15) {  // T14: issue next-tile A loads + B glds before compute
      const int k1 = (c + 1) * 64;
#pragma unroll
      for (int it = 0; it < 4; ++it) {
        const float4* p = reinterpret_cast<const float4*>(
            A + (size_t)(bm + srow + it * 32) * K + k1 + scole);
        fa[2 * it] = p[0];
        fa[2 * it + 1] = p[1];
      }
      stageB(k1, buf ^ 1);
    }
    GEMM_COMPUTE_HALF(buf, 0)
    GEMM_COMPUTE_HALF(buf, 1)
    if (c < 15) {  // write-late A
#pragma unroll
      for (int it = 0; it < 4; ++it) STA(buf ^ 1, it, cvt8(fa[2 * it], fa[2 * it + 1]));
    }
    __syncthreads();
  }

#pragma unroll
  for (int m = 0; m < 4; ++m) {
    const int mr = bm + wr * 64 + m * 16 + lg * 4;
#pragma unroll
    for (int nt = 0; nt < 2; ++nt) {
      const int n = bn + wc * 32 + nt * 16 + lr;
      const float bb = bias[n];
      if (z == 0) {
#pragma unroll
        for (int r = 0; r < 4; ++r)
          Qb[(size_t)(mr + r) * N + n] = f2b((acc[m][nt][r] + bb) * qscale);
      } else if (z == 1) {
        // Kf: K[bh][s][d] -> bh*65536 + (d>>5)*32768 + (s>>4)*512
        //     + ((s&15)|(((d>>3)&3)<<4))*8 + (d&7)
        const int b2 = mr >> 10, s0 = mr & 1023, hh = n >> 6, dd = n & 63;
        const size_t base = (size_t)(b2 * 16 + hh) * 65536 + (size_t)(dd >> 5) * 32768 +
                            (size_t)(s0 >> 4) * 512 +
                            (size_t)((s0 & 15) | (((dd >> 3) & 3) << 4)) * 8 + (dd & 7);
#pragma unroll
        for (int r = 0; r < 4; ++r) Kf[base + r * 8] = f2b(acc[m][nt][r] + bb);
      } else {
        // Vf: V[bh][s][d] -> bh*65536 + (s>>5)*2048 + (d>>4)*512
        //     + ((d&15)|(((s>>3)&3)<<4))*8 + (s&7)
        const int b2 = mr >> 10, s0 = mr & 1023, hh = n >> 6, dd = n & 63;
        const size_t base = (size_t)(b2 * 16 + hh) * 65536 + (size_t)(s0 >> 5) * 2048 +
                            (size_t)(dd >> 4) * 512 +
                            (size_t)((dd & 15) | (((s0 >> 3) & 3) << 4)) * 8 + (s0 & 7);
        us4 pk;
#pragma unroll
        for (int r = 0; r < 4; ++r) pk[r] = f2b(acc[m][nt][r] + bb);
        *reinterpret_cast<us4*>(&Vf[base]) = pk;
      }
    }
  }
}

// Output projection: both A (bf16 ctx) and B (bf16 wo) via swizzled-source glds.
__global__ __launch_bounds__(256)
void gemm_out(const unsigned short* __restrict__ A, const unsigned short* __restrict__ Bw,
              const float* __restrict__ bias, float* __restrict__ Out) {
  constexpr int K = 1024, N = 1024;
  __shared__ __align__(16) unsigned short As[2][128 * 64];
  __shared__ __align__(16) unsigned short Bs[2][64 * 64];
  const int bm = blockIdx.x * 128, bn = blockIdx.y * 64;
  const int t = threadIdx.x;
  const int w = t >> 6, lane = t & 63, lr = lane & 15, lg = lane >> 4;
  const int wr = w >> 1, wc = w & 1;
  const int swzc = (lr & 7) << 4;

  f32x4 acc[4][2];
#pragma unroll
  for (int m = 0; m < 4; ++m)
#pragma unroll
    for (int n = 0; n < 2; ++n) acc[m][n] = f32x4{0.f, 0.f, 0.f, 0.f};

  auto stageA = [&](int k0, int buf) {
#pragma unroll
    for (int it = 0; it < 4; ++it) {
      const int s = it * 256 + t, row = s >> 3, cb = (s & 7) * 16;
      const char* g = (const char*)A + ((size_t)(bm + row) * 1024 + k0) * 2 +
                      (cb ^ ((row & 7) << 4));
      char* l = (char*)&As[buf][0] + (it * 256 + w * 64) * 16;
      glds16(g, l);
    }
  };
  auto stageB = [&](int k0, int buf) {
#pragma unroll
    for (int it = 0; it < 2; ++it) {
      const int s = it * 256 + t, row = s >> 3, cb = (s & 7) * 16;
      const char* g = (const char*)Bw + ((size_t)(bn + row) * 1024 + k0) * 2 +
                      (cb ^ ((row & 7) << 4));
      char* l = (char*)&Bs[buf][0] + (it * 256 + w * 64) * 16;
      glds16(g, l);
    }
  };

  stageA(0, 0);
  stageB(0, 0);
  __syncthreads();

  for (int c = 0; c < 16; ++c) {
    const int buf = c & 1;
    if (c < 15) {
      const int k1 = (c + 1) * 64;
      stageA(k1, buf ^ 1);
      stageB(k1, buf ^ 1);
    }
    GEMM_COMPUTE_HALF(buf, 0)
    GEMM_COMPUTE_HALF(buf, 1)
    __syncthreads();
  }

#pragma unroll
  for (int m = 0; m < 4; ++m) {
    const int mr = bm + wr * 64 + m * 16 + lg * 4;
#pragma unroll
    for (int nt = 0; nt < 2; ++nt) {
      const int n = bn + wc * 32 + nt * 16 + lr;
      const float bb = bias[n];
#pragma unroll
      for (int r = 0; r < 4; ++r) Out[(size_t)(mr + r) * N + n] = acc[m][nt][r] + bb;
    }
  }
}

// Flash attention v5 (unchanged): swapped QK^T, 16 q-rows/wave, 4 waves/WG.
__global__ __launch_bounds__(256)
void attn_v5(const unsigned short* __restrict__ Qb,
             const unsigned short* __restrict__ Kf,
             const unsigned short* __restrict__ Vf,
             const unsigned short* __restrict__ Mf,
             unsigned short* __restrict__ ctx) {
  __shared__ __align__(16) unsigned short sP[4][16 * 64];  // wave-private
  const int bh = blockIdx.x, b = bh >> 4, h = bh & 15;
  const int qb = blockIdx.y;
  const int t = threadIdx.x, w = t >> 6, wl = t & 63, lr = wl & 15, lg = wl >> 4;
  const int q0 = qb * 64 + w * 16;
  const int swz = (lr & 7) << 4;

  const unsigned short* qp = Qb + (size_t)(b * 1024 + q0 + lr) * 1024 + h * 64 + lg * 8;
  const bf16x8 bq0 = ldbf8(qp);
  const bf16x8 bq1 = ldbf8(qp + 32);

  const unsigned short* KfB = Kf + (size_t)bh * 65536;
  const unsigned short* VfB = Vf + (size_t)bh * 65536;
  const unsigned short* mfp = Mf + (size_t)((b * 64 + qb * 4 + w) * 64) * 256 + wl * 4;

  f32x4 O[4];
  float m_ = -3e38f, l_ = 0.f;
#pragma unroll
  for (int dt = 0; dt < 4; ++dt) O[dt] = f32x4{0.f, 0.f, 0.f, 0.f};
  unsigned short* sp = &sP[w][0];

  for (int kc = 0; kc < 16; ++kc) {
    bf16x8 ak[4][2];
#pragma unroll
    for (int t4 = 0; t4 < 4; ++t4) {
      ak[t4][0] = ldbf8(KfB + (size_t)(kc * 4 + t4) * 512 + wl * 8);
      ak[t4][1] = ldbf8(KfB + 32768 + (size_t)(kc * 4 + t4) * 512 + wl * 8);
    }
    us4 mk[4];
#pragma unroll
    for (int t4 = 0; t4 < 4; ++t4)
      mk[t4] = *reinterpret_cast<const us4*>(mfp + (size_t)(kc * 4 + t4) * 256);
    bf16x8 bv[2][4];
#pragma unroll
    for (int ks = 0; ks < 2; ++ks)
#pragma unroll
      for (int dt = 0; dt < 4; ++dt)
        bv[ks][dt] = ldbf8(VfB + (size_t)(kc * 2 + ks) * 2048 + dt * 512 + wl * 8);

    f32x4 sc[4];
#pragma unroll
    for (int t4 = 0; t4 < 4; ++t4) {
      f32x4 a;
#pragma unroll
      for (int r = 0; r < 4; ++r) a[r] = b2f(mk[t4][r]);
      a = MFMA(ak[t4][0], bq0, a);
      a = MFMA(ak[t4][1], bq1, a);
      sc[t4] = a;
    }

    float v0 = fmaxf(fmaxf(sc[0][0], sc[0][1]), fmaxf(sc[0][2], sc[0][3]));
    float v1 = fmaxf(fmaxf(sc[1][0], sc[1][1]), fmaxf(sc[1][2], sc[1][3]));
    float v2 = fmaxf(fmaxf(sc[2][0], sc[2][1]), fmaxf(sc[2][2], sc[2][3]));
    float v3 = fmaxf(fmaxf(sc[3][0], sc[3][1]), fmaxf(sc[3][2], sc[3][3]));
    float mc = fmaxf(fmaxf(v0, v1), fmaxf(v2, v3));
    mc = fmaxf(mc, __shfl_xor(mc, 16));
    mc = fmaxf(mc, __shfl_xor(mc, 32));
    if (__any(mc > m_ + 11.5f)) {  // T13 defer-rescale (log2 units)
      const float mn = fmaxf(m_, mc);
      const float sf = EXP2(m_ - mn);
      l_ *= sf;
      m_ = mn;
      float s4[4];
#pragma unroll
      for (int r = 0; r < 4; ++r) s4[r] = __shfl(sf, lg * 4 + r);
#pragma unroll
      for (int dt = 0; dt < 4; ++dt)
#pragma unroll
        for (int r = 0; r < 4; ++r) O[dt][r] *= s4[r];
    }
    float ps = 0.f;
#pragma unroll
    for (int t4 = 0; t4 < 4; ++t4) {
      us4 pw;
#pragma unroll
      for (int r = 0; r < 4; ++r) {
        const float e = EXP2(sc[t4][r] - m_);
        ps += e;
        pw[r] = f2b(e);
      }
      *reinterpret_cast<us4*>((char*)sp + lr * 128 + ((t4 * 32 + lg * 8) ^ swz)) = pw;
    }
    ps += __shfl_xor(ps, 16);
    ps += __shfl_xor(ps, 32);
    l_ += ps;

#pragma unroll
    for (int ks = 0; ks < 2; ++ks) {
      bf16x8 ap =
          ldbf8((const unsigned short*)((char*)sp + lr * 128 + ((ks * 64 + lg * 16) ^ swz)));
#pragma unroll
      for (int dt = 0; dt < 4; ++dt) O[dt] = MFMA(ap, bv[ks][dt], O[dt]);
    }
  }

  float linv[4];
#pragma unroll
  for (int r = 0; r < 4; ++r) linv[r] = 1.0f / __shfl(l_, lg * 4 + r);
#pragma unroll
  for (int dt = 0; dt < 4; ++dt)
#pragma unroll
    for (int r = 0; r < 4; ++r)
      ctx[(size_t)(b * 1024 + q0 + lg * 4 + r) * 1024 + h * 64 + dt * 16 + lr] =
          f2b(O[dt][r] * linv[r]);
}

extern "C" void kernel_launch(void* const* d_in, const int* in_sizes, int n_in,
                              void* d_out, int out_size, void* d_ws, size_t ws_size,
                              hipStream_t stream) {
  const float* query = (const float*)d_in[0];
  const float* key   = (const float*)d_in[1];
  const float* value = (const float*)d_in[2];
  const int*   mask  = (const int*)d_in[3];
  const float* wq = (const float*)d_in[4];
  const float* bq = (const float*)d_in[5];
  const float* wk = (const float*)d_in[6];
  const float* bk = (const float*)d_in[7];
  const float* wv = (const float*)d_in[8];
  const float* bv = (const float*)d_in[9];
  const float* wo = (const float*)d_in[10];
  const float* bo = (const float*)d_in[11];
  float* out = (float*)d_out;

  // ws (32 MB): Qb, Kf, Vf, ctx — bf16, 8 MB each.
  // d_out (16 MB): Mf (8 MB) + Wb q/k/v bf16 (6 MB); both dead before gemm_out
  // overwrites d_out. wo(bf16) is converted into Vf's space after attn.
  const size_t SZ = (size_t)4096 * 1024;
  unsigned short* Qb  = (unsigned short*)d_ws;
  unsigned short* Kf  = Qb + SZ;
  unsigned short* Vf  = Kf + SZ;
  unsigned short* ctx = Vf + SZ;
  unsigned short* Mf  = (unsigned short*)d_out;
  unsigned short* Wb  = Mf + SZ;
  unsigned short* Wob = Vf;  // reused after attn

  const float qscale = 0.125f * 1.4426950408889634f;  // 1/sqrt(64) * log2(e)
  dim3 blk(256);
  prep<<<5632, blk, 0, stream>>>(mask, wq, wk, wv, Mf, Wb);
  gemm_qkv<<<dim3(32, 16, 3), blk, 0, stream>>>(query, key, value, Wb, bq, bk, bv,
                                                Qb, Kf, Vf, qscale);
  attn_v5<<<dim3(64, 16), blk, 0, stream>>>(Qb, Kf, Vf, Mf, ctx);
  cvt_w<<<512, blk, 0, stream>>>(wo, Wob);
  gemm_out<<<dim3(32, 16), blk, 0, stream>>>(ctx, Wob, bo, out);
}

// Round 7
// 130.083 us; speedup vs baseline: 1.0522x; 1.0522x over previous
//
#include <hip/hip_runtime.h>
#include <hip/hip_bf16.h>

// MHA forward: B=4, S=1024, D=1024, H=16, DK=64.
// v7: XCD-aware chunk swizzle (T1) on gemm_qkv/gemm_out/attn so co-resident
// WGs per XCD share A-panels + weights in that XCD's L2. Rest = v6.

typedef __bf16 bf16x8 __attribute__((ext_vector_type(8)));
typedef float f32x4 __attribute__((ext_vector_type(4)));
typedef unsigned short us8 __attribute__((ext_vector_type(8)));
typedef unsigned short us4 __attribute__((ext_vector_type(4)));

#define MFMA(a, b, c) __builtin_amdgcn_mfma_f32_16x16x32_bf16(a, b, c, 0, 0, 0)
#define EXP2(x) __builtin_amdgcn_exp2f(x)

__device__ __forceinline__ unsigned short f2b(float f) {
  return __builtin_bit_cast(unsigned short, __float2bfloat16(f));
}
__device__ __forceinline__ float b2f(unsigned short u) {
  return __builtin_bit_cast(float, (unsigned)u << 16);
}
__device__ __forceinline__ bf16x8 ldbf8(const unsigned short* p) {
  return __builtin_bit_cast(bf16x8, *reinterpret_cast<const us8*>(p));
}
__device__ __forceinline__ us8 cvt8(float4 a, float4 b) {
  us8 o;
  o[0] = f2b(a.x); o[1] = f2b(a.y); o[2] = f2b(a.z); o[3] = f2b(a.w);
  o[4] = f2b(b.x); o[5] = f2b(b.y); o[6] = f2b(b.z); o[7] = f2b(b.w);
  return o;
}
__device__ __forceinline__ void glds16(const void* g, void* l) {
  __builtin_amdgcn_global_load_lds(
      (const __attribute__((address_space(1))) unsigned int*)g,
      (__attribute__((address_space(3))) unsigned int*)l, 16, 0, 0);
}

// prep: [0,4096) blocks convert mask -> Mf (swapped QK^T C-frag order, *(-1e9*log2e));
//       [4096,5632) convert wq/wk/wv f32 -> bf16 into Wb (3 x 1M elements).
__global__ __launch_bounds__(256)
void prep(const int* __restrict__ mask, const float* __restrict__ wq,
          const float* __restrict__ wk, const float* __restrict__ wv,
          unsigned short* __restrict__ Mf, unsigned short* __restrict__ Wb) {
  const int bid = blockIdx.x, tid = threadIdx.x;
  if (bid < 4096) {
    const int idx = bid * 256 + tid;
    const int wl = idx & 63, tile = idx >> 6;
    const int kt = tile & 63, qt = (tile >> 6) & 63, b = tile >> 12;
    const int lr = wl & 15, lg = wl >> 4;
    const int4 mv = *reinterpret_cast<const int4*>(
        mask + (size_t)(b * 1024 + qt * 16 + lr) * 1024 + kt * 16 + lg * 4);
    us4 o;
    o[0] = mv.x ? 0xCEACu : 0u;
    o[1] = mv.y ? 0xCEACu : 0u;
    o[2] = mv.z ? 0xCEACu : 0u;
    o[3] = mv.w ? 0xCEACu : 0u;
    *reinterpret_cast<us4*>(Mf + (size_t)idx * 4) = o;
  } else {
    const int b2 = bid - 4096;
    const int widx = b2 >> 9;
    const float* src = (widx == 0) ? wq : (widx == 1) ? wk : wv;
    const size_t off = (size_t)(b2 & 511) * 2048 + tid * 8;
    const float4* p = reinterpret_cast<const float4*>(src + off);
    *reinterpret_cast<us8*>(Wb + (size_t)widx * 1048576 + off) = cvt8(p[0], p[1]);
  }
}

// single f32->bf16 1Mx convert (for wo, after attn frees Vf space)
__global__ __launch_bounds__(256)
void cvt_w(const float* __restrict__ src, unsigned short* __restrict__ dst) {
  const size_t off = (size_t)blockIdx.x * 2048 + threadIdx.x * 8;
  const float4* p = reinterpret_cast<const float4*>(src + off);
  *reinterpret_cast<us8*>(dst + off) = cvt8(p[0], p[1]);
}

// ---- shared compute macro: As [128][64] / Bs [64][64] bf16, XOR-swizzled rows,
// 4 waves 2x2 (wave tile 64x32). Reads apply byte^((row&7)<<4).
#define GEMM_COMPUTE_HALF(buf, h2)                                             \
  {                                                                            \
    bf16x8 af[4], bfr[2];                                                      \
    _Pragma("unroll") for (int m = 0; m < 4; ++m) {                            \
      const int row = wr * 64 + m * 16 + lr;                                   \
      af[m] = ldbf8((const unsigned short*)((char*)&As[buf][0] + row * 128 +   \
                                            (((h2) * 64 + lg * 16) ^ swzc)));  \
    }                                                                          \
    _Pragma("unroll") for (int n = 0; n < 2; ++n) {                            \
      const int row = wc * 32 + n * 16 + lr;                                   \
      bfr[n] = ldbf8((const unsigned short*)((char*)&Bs[buf][0] + row * 128 +  \
                                             (((h2) * 64 + lg * 16) ^ swzc))); \
    }                                                                          \
    _Pragma("unroll") for (int m = 0; m < 4; ++m)                              \
        _Pragma("unroll") for (int n = 0; n < 2; ++n)                          \
        acc[m][n] = MFMA(af[m], bfr[n], acc[m][n]);                            \
  }

#define STA(buf, it, v)                                                        \
  *reinterpret_cast<us8*>((char*)&As[buf][0] + (srow + (it) * 32) * 128 +      \
                          (scolb ^ (((srow + (it) * 32) & 7) << 4))) = (v)

// Fused QKV projection. A: f32 (reg-staged, T14 split); B: bf16 weights via
// swizzled-source global_load_lds. XCD chunk swizzle: chunk = {z, 2 bm} x 16 bn.
__global__ __launch_bounds__(256)
void gemm_qkv(const float* __restrict__ Aq, const float* __restrict__ Akk,
              const float* __restrict__ Av, const unsigned short* __restrict__ Wb,
              const float* __restrict__ bq, const float* __restrict__ bk,
              const float* __restrict__ bv, unsigned short* __restrict__ Qb,
              unsigned short* __restrict__ Kf, unsigned short* __restrict__ Vf,
              float qscale) {
  constexpr int K = 1024, N = 1024;
  __shared__ __align__(16) unsigned short As[2][128 * 64];
  __shared__ __align__(16) unsigned short Bs[2][64 * 64];
  // T1 swizzle: lid in [0,1536); xcd = lid%8; chunk = (slot/32)*8+xcd in [0,48);
  // z = chunk/16, bm-pair = chunk%16, pos = slot%32 -> bm = pair*2+pos/16, bn = pos%16.
  const int lid = blockIdx.x + (blockIdx.y << 5) + (blockIdx.z << 9);
  const int xcd = lid & 7, slot = lid >> 3;
  const int chunk = ((slot >> 5) << 3) + xcd;
  const int pos = slot & 31;
  const int z = chunk >> 4;
  const int bm = (((chunk & 15) << 1) + (pos >> 4)) * 128;
  const int bn = (pos & 15) * 64;

  const float* A = (z == 0) ? Aq : (z == 1) ? Akk : Av;
  const unsigned short* Bw = Wb + (size_t)z * 1048576;
  const float* bias = (z == 0) ? bq : (z == 1) ? bk : bv;
  const int t = threadIdx.x;
  const int w = t >> 6, lane = t & 63, lr = lane & 15, lg = lane >> 4;
  const int wr = w >> 1, wc = w & 1;
  const int srow = t >> 3, scolb = (t & 7) * 16, scole = (t & 7) * 8;
  const int swzc = (lr & 7) << 4;

  f32x4 acc[4][2];
#pragma unroll
  for (int m = 0; m < 4; ++m)
#pragma unroll
    for (int n = 0; n < 2; ++n) acc[m][n] = f32x4{0.f, 0.f, 0.f, 0.f};

  // B staging: pre-swizzled global source + linear glds dest (rule #21)
  auto stageB = [&](int k0, int buf) {
#pragma unroll
    for (int it = 0; it < 2; ++it) {
      const int s = it * 256 + t, row = s >> 3, cb = (s & 7) * 16;
      const char* g = (const char*)Bw + ((size_t)(bn + row) * 1024 + k0) * 2 +
                      (cb ^ ((row & 7) << 4));
      char* l = (char*)&Bs[buf][0] + (it * 256 + w * 64) * 16;
      glds16(g, l);
    }
  };

  // prologue
  {
#pragma unroll
    for (int it = 0; it < 4; ++it) {
      const float4* p =
          reinterpret_cast<const float4*>(A + (size_t)(bm + srow + it * 32) * K + scole);
      STA(0, it, cvt8(p[0], p[1]));
    }
    stageB(0, 0);
  }
  __syncthreads();

  for (int c = 0; c < 16; ++c) {
    const int buf = c & 1;
    float4 fa[8];
    if (c < 15) {  // T14: issue next-tile A loads + B glds before compute
      const int k1 = (c + 1) * 64;
#pragma unroll
      for (int it = 0; it < 4; ++it) {
        const float4* p = reinterpret_cast<const float4*>(
            A + (size_t)(bm + srow + it * 32) * K + k1 + scole);
        fa[2 * it] = p[0];
        fa[2 * it + 1] = p[1];
      }
      stageB(k1, buf ^ 1);
    }
    GEMM_COMPUTE_HALF(buf, 0)
    GEMM_COMPUTE_HALF(buf, 1)
    if (c < 15) {  // write-late A
#pragma unroll
      for (int it = 0; it < 4; ++it) STA(buf ^ 1, it, cvt8(fa[2 * it], fa[2 * it + 1]));
    }
    __syncthreads();
  }

#pragma unroll
  for (int m = 0; m < 4; ++m) {
    const int mr = bm + wr * 64 + m * 16 + lg * 4;
#pragma unroll
    for (int nt = 0; nt < 2; ++nt) {
      const int n = bn + wc * 32 + nt * 16 + lr;
      const float bb = bias[n];
      if (z == 0) {
#pragma unroll
        for (int r = 0; r < 4; ++r)
          Qb[(size_t)(mr + r) * N + n] = f2b((acc[m][nt][r] + bb) * qscale);
      } else if (z == 1) {
        // Kf: K[bh][s][d] -> bh*65536 + (d>>5)*32768 + (s>>4)*512
        //     + ((s&15)|(((d>>3)&3)<<4))*8 + (d&7)
        const int b2 = mr >> 10, s0 = mr & 1023, hh = n >> 6, dd = n & 63;
        const size_t base = (size_t)(b2 * 16 + hh) * 65536 + (size_t)(dd >> 5) * 32768 +
                            (size_t)(s0 >> 4) * 512 +
                            (size_t)((s0 & 15) | (((dd >> 3) & 3) << 4)) * 8 + (dd & 7);
#pragma unroll
        for (int r = 0; r < 4; ++r) Kf[base + r * 8] = f2b(acc[m][nt][r] + bb);
      } else {
        // Vf: V[bh][s][d] -> bh*65536 + (s>>5)*2048 + (d>>4)*512
        //     + ((d&15)|(((s>>3)&3)<<4))*8 + (s&7)
        const int b2 = mr >> 10, s0 = mr & 1023, hh = n >> 6, dd = n & 63;
        const size_t base = (size_t)(b2 * 16 + hh) * 65536 + (size_t)(s0 >> 5) * 2048 +
                            (size_t)(dd >> 4) * 512 +
                            (size_t)((dd & 15) | (((s0 >> 3) & 3) << 4)) * 8 + (s0 & 7);
        us4 pk;
#pragma unroll
        for (int r = 0; r < 4; ++r) pk[r] = f2b(acc[m][nt][r] + bb);
        *reinterpret_cast<us4*>(&Vf[base]) = pk;
      }
    }
  }
}

// Output projection: both A (bf16 ctx) and B (bf16 wo) via swizzled-source glds.
// XCD chunk swizzle: chunk = 2 bm x 16 bn (2.5 MB working set per chunk).
__global__ __launch_bounds__(256)
void gemm_out(const unsigned short* __restrict__ A, const unsigned short* __restrict__ Bw,
              const float* __restrict__ bias, float* __restrict__ Out) {
  constexpr int K = 1024, N = 1024;
  __shared__ __align__(16) unsigned short As[2][128 * 64];
  __shared__ __align__(16) unsigned short Bs[2][64 * 64];
  const int lid = blockIdx.x + (blockIdx.y << 5);
  const int xcd = lid & 7, slot = lid >> 3;
  const int chunk = ((slot >> 5) << 3) + xcd;  // 0..15
  const int pos = slot & 31;
  const int bm = ((chunk << 1) + (pos >> 4)) * 128;
  const int bn = (pos & 15) * 64;
  const int t = threadIdx.x;
  const int w = t >> 6, lane = t & 63, lr = lane & 15, lg = lane >> 4;
  const int wr = w >> 1, wc = w & 1;
  const int swzc = (lr & 7) << 4;

  f32x4 acc[4][2];
#pragma unroll
  for (int m = 0; m < 4; ++m)
#pragma unroll
    for (int n = 0; n < 2; ++n) acc[m][n] = f32x4{0.f, 0.f, 0.f, 0.f};

  auto stageA = [&](int k0, int buf) {
#pragma unroll
    for (int it = 0; it < 4; ++it) {
      const int s = it * 256 + t, row = s >> 3, cb = (s & 7) * 16;
      const char* g = (const char*)A + ((size_t)(bm + row) * 1024 + k0) * 2 +
                      (cb ^ ((row & 7) << 4));
      char* l = (char*)&As[buf][0] + (it * 256 + w * 64) * 16;
      glds16(g, l);
    }
  };
  auto stageB = [&](int k0, int buf) {
#pragma unroll
    for (int it = 0; it < 2; ++it) {
      const int s = it * 256 + t, row = s >> 3, cb = (s & 7) * 16;
      const char* g = (const char*)Bw + ((size_t)(bn + row) * 1024 + k0) * 2 +
                      (cb ^ ((row & 7) << 4));
      char* l = (char*)&Bs[buf][0] + (it * 256 + w * 64) * 16;
      glds16(g, l);
    }
  };

  stageA(0, 0);
  stageB(0, 0);
  __syncthreads();

  for (int c = 0; c < 16; ++c) {
    const int buf = c & 1;
    if (c < 15) {
      const int k1 = (c + 1) * 64;
      stageA(k1, buf ^ 1);
      stageB(k1, buf ^ 1);
    }
    GEMM_COMPUTE_HALF(buf, 0)
    GEMM_COMPUTE_HALF(buf, 1)
    __syncthreads();
  }

#pragma unroll
  for (int m = 0; m < 4; ++m) {
    const int mr = bm + wr * 64 + m * 16 + lg * 4;
#pragma unroll
    for (int nt = 0; nt < 2; ++nt) {
      const int n = bn + wc * 32 + nt * 16 + lr;
      const float bb = bias[n];
#pragma unroll
      for (int r = 0; r < 4; ++r) Out[(size_t)(mr + r) * N + n] = acc[m][nt][r] + bb;
    }
  }
}

// Flash attention v5 + XCD swizzle: chunk = 1 bh x 16 qb (K/V L2-resident).
__global__ __launch_bounds__(256)
void attn_v5(const unsigned short* __restrict__ Qb,
             const unsigned short* __restrict__ Kf,
             const unsigned short* __restrict__ Vf,
             const unsigned short* __restrict__ Mf,
             unsigned short* __restrict__ ctx) {
  __shared__ __align__(16) unsigned short sP[4][16 * 64];  // wave-private
  const int lid = blockIdx.x + (blockIdx.y << 6);
  const int xcd = lid & 7, slot = lid >> 3;
  const int bh = ((slot >> 4) << 3) + xcd;  // 0..63
  const int qb = slot & 15;
  const int b = bh >> 4, h = bh & 15;
  const int t = threadIdx.x, w = t >> 6, wl = t & 63, lr = wl & 15, lg = wl >> 4;
  const int q0 = qb * 64 + w * 16;
  const int swz = (lr & 7) << 4;

  const unsigned short* qp = Qb + (size_t)(b * 1024 + q0 + lr) * 1024 + h * 64 + lg * 8;
  const bf16x8 bq0 = ldbf8(qp);
  const bf16x8 bq1 = ldbf8(qp + 32);

  const unsigned short* KfB = Kf + (size_t)bh * 65536;
  const unsigned short* VfB = Vf + (size_t)bh * 65536;
  const unsigned short* mfp = Mf + (size_t)((b * 64 + qb * 4 + w) * 64) * 256 + wl * 4;

  f32x4 O[4];
  float m_ = -3e38f, l_ = 0.f;
#pragma unroll
  for (int dt = 0; dt < 4; ++dt) O[dt] = f32x4{0.f, 0.f, 0.f, 0.f};
  unsigned short* sp = &sP[w][0];

  for (int kc = 0; kc < 16; ++kc) {
    bf16x8 ak[4][2];
#pragma unroll
    for (int t4 = 0; t4 < 4; ++t4) {
      ak[t4][0] = ldbf8(KfB + (size_t)(kc * 4 + t4) * 512 + wl * 8);
      ak[t4][1] = ldbf8(KfB + 32768 + (size_t)(kc * 4 + t4) * 512 + wl * 8);
    }
    us4 mk[4];
#pragma unroll
    for (int t4 = 0; t4 < 4; ++t4)
      mk[t4] = *reinterpret_cast<const us4*>(mfp + (size_t)(kc * 4 + t4) * 256);
    bf16x8 bv[2][4];
#pragma unroll
    for (int ks = 0; ks < 2; ++ks)
#pragma unroll
      for (int dt = 0; dt < 4; ++dt)
        bv[ks][dt] = ldbf8(VfB + (size_t)(kc * 2 + ks) * 2048 + dt * 512 + wl * 8);

    f32x4 sc[4];
#pragma unroll
    for (int t4 = 0; t4 < 4; ++t4) {
      f32x4 a;
#pragma unroll
      for (int r = 0; r < 4; ++r) a[r] = b2f(mk[t4][r]);
      a = MFMA(ak[t4][0], bq0, a);
      a = MFMA(ak[t4][1], bq1, a);
      sc[t4] = a;
    }

    float v0 = fmaxf(fmaxf(sc[0][0], sc[0][1]), fmaxf(sc[0][2], sc[0][3]));
    float v1 = fmaxf(fmaxf(sc[1][0], sc[1][1]), fmaxf(sc[1][2], sc[1][3]));
    float v2 = fmaxf(fmaxf(sc[2][0], sc[2][1]), fmaxf(sc[2][2], sc[2][3]));
    float v3 = fmaxf(fmaxf(sc[3][0], sc[3][1]), fmaxf(sc[3][2], sc[3][3]));
    float mc = fmaxf(fmaxf(v0, v1), fmaxf(v2, v3));
    mc = fmaxf(mc, __shfl_xor(mc, 16));
    mc = fmaxf(mc, __shfl_xor(mc, 32));
    if (__any(mc > m_ + 11.5f)) {  // T13 defer-rescale (log2 units)
      const float mn = fmaxf(m_, mc);
      const float sf = EXP2(m_ - mn);
      l_ *= sf;
      m_ = mn;
      float s4[4];
#pragma unroll
      for (int r = 0; r < 4; ++r) s4[r] = __shfl(sf, lg * 4 + r);
#pragma unroll
      for (int dt = 0; dt < 4; ++dt)
#pragma unroll
        for (int r = 0; r < 4; ++r) O[dt][r] *= s4[r];
    }
    float ps = 0.f;
#pragma unroll
    for (int t4 = 0; t4 < 4; ++t4) {
      us4 pw;
#pragma unroll
      for (int r = 0; r < 4; ++r) {
        const float e = EXP2(sc[t4][r] - m_);
        ps += e;
        pw[r] = f2b(e);
      }
      *reinterpret_cast<us4*>((char*)sp + lr * 128 + ((t4 * 32 + lg * 8) ^ swz)) = pw;
    }
    ps += __shfl_xor(ps, 16);
    ps += __shfl_xor(ps, 32);
    l_ += ps;

#pragma unroll
    for (int ks = 0; ks < 2; ++ks) {
      bf16x8 ap =
          ldbf8((const unsigned short*)((char*)sp + lr * 128 + ((ks * 64 + lg * 16) ^ swz)));
#pragma unroll
      for (int dt = 0; dt < 4; ++dt) O[dt] = MFMA(ap, bv[ks][dt], O[dt]);
    }
  }

  float linv[4];
#pragma unroll
  for (int r = 0; r < 4; ++r) linv[r] = 1.0f / __shfl(l_, lg * 4 + r);
#pragma unroll
  for (int dt = 0; dt < 4; ++dt)
#pragma unroll
    for (int r = 0; r < 4; ++r)
      ctx[(size_t)(b * 1024 + q0 + lg * 4 + r) * 1024 + h * 64 + dt * 16 + lr] =
          f2b(O[dt][r] * linv[r]);
}

extern "C" void kernel_launch(void* const* d_in, const int* in_sizes, int n_in,
                              void* d_out, int out_size, void* d_ws, size_t ws_size,
                              hipStream_t stream) {
  const float* query = (const float*)d_in[0];
  const float* key   = (const float*)d_in[1];
  const float* value = (const float*)d_in[2];
  const int*   mask  = (const int*)d_in[3];
  const float* wq = (const float*)d_in[4];
  const float* bq = (const float*)d_in[5];
  const float* wk = (const float*)d_in[6];
  const float* bk = (const float*)d_in[7];
  const float* wv = (const float*)d_in[8];
  const float* bv = (const float*)d_in[9];
  const float* wo = (const float*)d_in[10];
  const float* bo = (const float*)d_in[11];
  float* out = (float*)d_out;

  // ws (32 MB): Qb, Kf, Vf, ctx — bf16, 8 MB each.
  // d_out (16 MB): Mf (8 MB) + Wb q/k/v bf16 (6 MB); both dead before gemm_out
  // overwrites d_out. wo(bf16) is converted into Vf's space after attn.
  const size_t SZ = (size_t)4096 * 1024;
  unsigned short* Qb  = (unsigned short*)d_ws;
  unsigned short* Kf  = Qb + SZ;
  unsigned short* Vf  = Kf + SZ;
  unsigned short* ctx = Vf + SZ;
  unsigned short* Mf  = (unsigned short*)d_out;
  unsigned short* Wb  = Mf + SZ;
  unsigned short* Wob = Vf;  // reused after attn

  const float qscale = 0.125f * 1.4426950408889634f;  // 1/sqrt(64) * log2(e)
  dim3 blk(256);
  prep<<<5632, blk, 0, stream>>>(mask, wq, wk, wv, Mf, Wb);
  gemm_qkv<<<dim3(32, 16, 3), blk, 0, stream>>>(query, key, value, Wb, bq, bk, bv,
                                                Qb, Kf, Vf, qscale);
  attn_v5<<<dim3(64, 16), blk, 0, stream>>>(Qb, Kf, Vf, Mf, ctx);
  cvt_w<<<512, blk, 0, stream>>>(wo, Wob);
  gemm_out<<<dim3(32, 16), blk, 0, stream>>>(ctx, Wob, bo, out);
}